// Round 1
// baseline (1237.965 us; speedup 1.0000x reference)
//
#include <hip/hip_runtime.h>
#include <math.h>

// ---------------------------------------------------------------------------
// GCN: 3x GCNConv(64->64) + ReLU, global mean pool (512 graphs), FC(64->8),
// sigmoid. N=100000 nodes, E=1250000 edges.
//
// ws layout (floats):
//   bufA   : N*64   (layer activations, ping)
//   bufB   : N*64   (layer activations, pong)
//   htmp   : N*64   (h = X@W, pre-aggregation)
//   dinv   : N      (deg^-1/2; reused: first holds deg)
//   pooled : G*64
//   cnt    : G
// total ~77.3 MB
// ---------------------------------------------------------------------------

#define FEAT 64

__global__ void k_init_deg(float* __restrict__ deg, int n) {
    int i = blockIdx.x * blockDim.x + threadIdx.x;
    if (i < n) deg[i] = 1.0f;  // self-loop
}

__global__ void k_count_deg(const int* __restrict__ ei, float* __restrict__ deg, int E) {
    int e = blockIdx.x * blockDim.x + threadIdx.x;
    if (e < E) atomicAdd(&deg[ei[E + e]], 1.0f);  // dst = ei[1][e]
}

__global__ void k_rsqrt(float* __restrict__ deg, int n) {
    int i = blockIdx.x * blockDim.x + threadIdx.x;
    if (i < n) deg[i] = rsqrtf(deg[i]);
}

// h = X @ W ; out_init = h * dinv^2 + b   (self-loop term + bias pre-filled)
__global__ void k_matmul_init(const float* __restrict__ X, const float* __restrict__ W,
                              const float* __restrict__ b, const float* __restrict__ dinv,
                              float* __restrict__ h, float* __restrict__ out, int n) {
    __shared__ float Ws[FEAT][FEAT];
    __shared__ float Xs[4][FEAT];
    int f = threadIdx.x & 63;
    int r = threadIdx.x >> 6;  // 0..3
    // stage W (16 KB) once per block
    for (int i = threadIdx.x; i < FEAT * FEAT; i += 256) Ws[i >> 6][i & 63] = W[i];
    float bf = b[f];
    int ntiles = (n + 3) >> 2;
    for (int tile = blockIdx.x; tile < ntiles; tile += gridDim.x) {
        int row = (tile << 2) + r;
        __syncthreads();  // protects Ws (first iter) and Xs reuse
        if (row < n) Xs[r][f] = X[(size_t)row * FEAT + f];
        __syncthreads();
        if (row < n) {
            float acc = 0.f;
            #pragma unroll
            for (int k = 0; k < FEAT; ++k) acc += Xs[r][k] * Ws[k][f];
            float dv = dinv[row];
            size_t o = (size_t)row * FEAT + f;
            h[o] = acc;
            out[o] = acc * dv * dv + bf;
        }
    }
}

// out[dst] += h[src] * dinv[src]*dinv[dst]   (one wave64 = one edge's 64 feats)
__global__ void k_edge(const int* __restrict__ ei, const float* __restrict__ dinv,
                       const float* __restrict__ h, float* __restrict__ out, int E) {
    int tid = blockIdx.x * blockDim.x + threadIdx.x;
    int e = tid >> 6;
    int f = tid & 63;
    if (e < E) {
        int s = ei[e];
        int d = ei[E + e];
        float coef = dinv[s] * dinv[d];
        atomicAdd(&out[(size_t)d * FEAT + f], h[(size_t)s * FEAT + f] * coef);
    }
}

__global__ void k_relu(float* __restrict__ out, int n64) {
    int i = blockIdx.x * blockDim.x + threadIdx.x;
    if (i < n64) out[i] = fmaxf(out[i], 0.f);
}

__global__ void k_zero(float* __restrict__ p, int n) {
    int i = blockIdx.x * blockDim.x + threadIdx.x;
    if (i < n) p[i] = 0.f;
}

__global__ void k_pool(const float* __restrict__ h, const int* __restrict__ batch,
                       float* __restrict__ pooled, float* __restrict__ cnt, int n) {
    int tid = blockIdx.x * blockDim.x + threadIdx.x;
    int i = tid >> 6;
    int f = tid & 63;
    if (i < n) {
        int g = batch[i];
        atomicAdd(&pooled[(size_t)g * FEAT + f], h[(size_t)i * FEAT + f]);
        if (f == 0) atomicAdd(&cnt[g], 1.0f);
    }
}

__global__ void k_fc_sigmoid(const float* __restrict__ pooled, const float* __restrict__ cnt,
                             const float* __restrict__ Wfc, const float* __restrict__ bfc,
                             float* __restrict__ out, int G) {
    __shared__ float P[FEAT];
    int g = blockIdx.x;
    int t = threadIdx.x;
    float c = fmaxf(cnt[g], 1.0f);
    P[t] = pooled[(size_t)g * FEAT + t] / c;
    __syncthreads();
    if (t < 8) {
        float acc = bfc[t];
        #pragma unroll
        for (int f = 0; f < FEAT; ++f) acc += P[f] * Wfc[f * 8 + t];
        out[(size_t)g * 8 + t] = 1.f / (1.f + expf(-acc));
    }
}

extern "C" void kernel_launch(void* const* d_in, const int* in_sizes, int n_in,
                              void* d_out, int out_size, void* d_ws, size_t ws_size,
                              hipStream_t stream) {
    const float* x    = (const float*)d_in[0];
    const int*   ei   = (const int*)d_in[1];
    const int*   batch= (const int*)d_in[2];
    const float* W0   = (const float*)d_in[3];
    const float* b0   = (const float*)d_in[4];
    const float* W1   = (const float*)d_in[5];
    const float* b1   = (const float*)d_in[6];
    const float* W2   = (const float*)d_in[7];
    const float* b2   = (const float*)d_in[8];
    const float* Wfc  = (const float*)d_in[9];
    const float* bfc  = (const float*)d_in[10];
    float* out = (float*)d_out;

    const int N = in_sizes[0] / FEAT;   // 100000
    const int E = in_sizes[1] / 2;      // 1250000
    const int G = out_size / 8;         // 512

    float* ws     = (float*)d_ws;
    float* bufA   = ws;
    float* bufB   = bufA + (size_t)N * FEAT;
    float* htmp   = bufB + (size_t)N * FEAT;
    float* dinv   = htmp + (size_t)N * FEAT;
    float* pooled = dinv + N;
    float* cnt    = pooled + (size_t)G * FEAT;

    const int TB = 256;
    dim3 blk(TB);

    // --- degree / normalization ---
    k_init_deg<<<dim3((N + TB - 1) / TB), blk, 0, stream>>>(dinv, N);
    k_count_deg<<<dim3((E + TB - 1) / TB), blk, 0, stream>>>(ei, dinv, E);
    k_rsqrt<<<dim3((N + TB - 1) / TB), blk, 0, stream>>>(dinv, N);

    const int n64 = N * FEAT;
    dim3 gEdge((E * FEAT + TB - 1) / TB);   // 312500 blocks
    dim3 gElem((n64 + TB - 1) / TB);
    dim3 gMM(2048);

    // --- layer 0: x -> bufA ---
    k_matmul_init<<<gMM, blk, 0, stream>>>(x, W0, b0, dinv, htmp, bufA, N);
    k_edge<<<gEdge, blk, 0, stream>>>(ei, dinv, htmp, bufA, E);
    k_relu<<<gElem, blk, 0, stream>>>(bufA, n64);

    // --- layer 1: bufA -> bufB ---
    k_matmul_init<<<gMM, blk, 0, stream>>>(bufA, W1, b1, dinv, htmp, bufB, N);
    k_edge<<<gEdge, blk, 0, stream>>>(ei, dinv, htmp, bufB, E);
    k_relu<<<gElem, blk, 0, stream>>>(bufB, n64);

    // --- layer 2: bufB -> bufA ---
    k_matmul_init<<<gMM, blk, 0, stream>>>(bufB, W2, b2, dinv, htmp, bufA, N);
    k_edge<<<gEdge, blk, 0, stream>>>(ei, dinv, htmp, bufA, E);
    k_relu<<<gElem, blk, 0, stream>>>(bufA, n64);

    // --- pooling + FC + sigmoid ---
    k_zero<<<dim3((G * (FEAT + 1) + TB - 1) / TB), blk, 0, stream>>>(pooled, G * (FEAT + 1));
    k_pool<<<gElem, blk, 0, stream>>>(bufA, batch, pooled, cnt, N);
    k_fc_sigmoid<<<dim3(G), dim3(FEAT), 0, stream>>>(pooled, cnt, Wfc, bfc, out, G);
}

// Round 2
// 652.852 us; speedup vs baseline: 1.8962x; 1.8962x over previous
//
#include <hip/hip_runtime.h>
#include <math.h>

// ---------------------------------------------------------------------------
// GCN: 3x GCNConv(64->64)+ReLU, mean pool (512 graphs), FC(64->8), sigmoid.
// N=100000, E=1250000. Strategy: build CSR-by-dst once per call, then
// gather-style aggregation (1 wave per dst node, no atomics on features).
// ---------------------------------------------------------------------------

#define FEAT 64

// ---- degree / CSR build ----------------------------------------------------

__global__ void k_zero_int(int* __restrict__ p, int n) {
    int i = blockIdx.x * blockDim.x + threadIdx.x;
    if (i < n) p[i] = 0;
}

__global__ void k_hist(const int* __restrict__ ei, int* __restrict__ deg, int E) {
    int e = blockIdx.x * blockDim.x + threadIdx.x;
    if (e < E) atomicAdd(&deg[ei[E + e]], 1);  // dst = ei[1][e]
}

__global__ void k_dinv(const int* __restrict__ deg, float* __restrict__ dinv, int n) {
    int i = blockIdx.x * blockDim.x + threadIdx.x;
    if (i < n) dinv[i] = rsqrtf((float)deg[i] + 1.0f);  // +1 self-loop
}

// single-block exclusive scan over deg -> off[0..N], cursor copy
__global__ void k_scan(const int* __restrict__ deg, int* __restrict__ off,
                       int* __restrict__ cursor, int N) {
    __shared__ int sdata[1024];
    __shared__ int carry;
    int tid = threadIdx.x;
    if (tid == 0) carry = 0;
    __syncthreads();
    for (int base = 0; base < N; base += 1024) {
        int i = base + tid;
        int v = (i < N) ? deg[i] : 0;
        sdata[tid] = v;
        __syncthreads();
        for (int d = 1; d < 1024; d <<= 1) {
            int t = (tid >= d) ? sdata[tid - d] : 0;
            __syncthreads();
            sdata[tid] += t;
            __syncthreads();
        }
        if (i < N) {
            int excl = carry + sdata[tid] - v;
            off[i] = excl;
            cursor[i] = excl;
        }
        __syncthreads();
        if (tid == 0) carry += sdata[1023];
        __syncthreads();
    }
    if (tid == 0) off[N] = carry;
}

__global__ void k_scatter(const int* __restrict__ ei, const float* __restrict__ dinv,
                          int* __restrict__ cursor, int* __restrict__ csr_src,
                          float* __restrict__ csr_coef, int E) {
    int e = blockIdx.x * blockDim.x + threadIdx.x;
    if (e < E) {
        int s = ei[e];
        int d = ei[E + e];
        int pos = atomicAdd(&cursor[d], 1);
        csr_src[pos] = s;
        csr_coef[pos] = dinv[s] * dinv[d];
    }
}

// ---- dense parts -----------------------------------------------------------

// h = X @ W ; out_init = h * dinv^2 + b   (self-loop term + bias pre-filled)
__global__ void k_matmul_init(const float* __restrict__ X, const float* __restrict__ W,
                              const float* __restrict__ b, const float* __restrict__ dinv,
                              float* __restrict__ h, float* __restrict__ out, int n) {
    __shared__ float Ws[FEAT][FEAT];
    __shared__ float Xs[4][FEAT];
    int f = threadIdx.x & 63;
    int r = threadIdx.x >> 6;  // 0..3
    for (int i = threadIdx.x; i < FEAT * FEAT; i += 256) Ws[i >> 6][i & 63] = W[i];
    float bf = b[f];
    int ntiles = (n + 3) >> 2;
    for (int tile = blockIdx.x; tile < ntiles; tile += gridDim.x) {
        int row = (tile << 2) + r;
        __syncthreads();
        if (row < n) Xs[r][f] = X[(size_t)row * FEAT + f];
        __syncthreads();
        if (row < n) {
            float acc = 0.f;
            #pragma unroll
            for (int k = 0; k < FEAT; ++k) acc += Xs[r][k] * Ws[k][f];
            float dv = dinv[row];
            size_t o = (size_t)row * FEAT + f;
            h[o] = acc;
            out[o] = acc * dv * dv + bf;
        }
    }
}

// out[dst] = relu(out[dst] + sum_j h[src_j]*coef_j)  -- 1 wave per dst node
__global__ void k_agg(const int* __restrict__ off, const int* __restrict__ csr_src,
                      const float* __restrict__ csr_coef, const float* __restrict__ h,
                      float* __restrict__ out, int N) {
    int node = blockIdx.x * (blockDim.x >> 6) + (threadIdx.x >> 6);
    int f = threadIdx.x & 63;
    if (node >= N) return;
    int j = off[node], e1 = off[node + 1];
    float acc = 0.f;
    for (; j + 4 <= e1; j += 4) {
        int s0 = csr_src[j], s1 = csr_src[j + 1], s2 = csr_src[j + 2], s3 = csr_src[j + 3];
        float c0 = csr_coef[j], c1 = csr_coef[j + 1], c2 = csr_coef[j + 2], c3 = csr_coef[j + 3];
        acc += h[(size_t)s0 * FEAT + f] * c0;
        acc += h[(size_t)s1 * FEAT + f] * c1;
        acc += h[(size_t)s2 * FEAT + f] * c2;
        acc += h[(size_t)s3 * FEAT + f] * c3;
    }
    for (; j < e1; ++j) acc += h[(size_t)csr_src[j] * FEAT + f] * csr_coef[j];
    size_t o = (size_t)node * FEAT + f;
    out[o] = fmaxf(out[o] + acc, 0.f);
}

// ---- pooling + FC ----------------------------------------------------------

__global__ void k_zero_f(float* __restrict__ p, int n) {
    int i = blockIdx.x * blockDim.x + threadIdx.x;
    if (i < n) p[i] = 0.f;
}

// batch is sorted: chunked per-wave reduction, flush on graph-id change
#define PCH 64
__global__ void k_pool(const float* __restrict__ h, const int* __restrict__ batch,
                       float* __restrict__ pooled, float* __restrict__ cnt, int N) {
    int wave = blockIdx.x * (blockDim.x >> 6) + (threadIdx.x >> 6);
    int f = threadIdx.x & 63;
    int start = wave * PCH;
    if (start >= N) return;
    int end = start + PCH; if (end > N) end = N;
    int cur = batch[start];
    float acc = 0.f;
    int nl = 0;
    for (int i = start; i < end; ++i) {
        int g = batch[i];
        if (g != cur) {
            atomicAdd(&pooled[(size_t)cur * FEAT + f], acc);
            if (f == 0) atomicAdd(&cnt[cur], (float)nl);
            cur = g; acc = 0.f; nl = 0;
        }
        acc += h[(size_t)i * FEAT + f];
        nl++;
    }
    atomicAdd(&pooled[(size_t)cur * FEAT + f], acc);
    if (f == 0) atomicAdd(&cnt[cur], (float)nl);
}

__global__ void k_fc_sigmoid(const float* __restrict__ pooled, const float* __restrict__ cnt,
                             const float* __restrict__ Wfc, const float* __restrict__ bfc,
                             float* __restrict__ out, int G) {
    __shared__ float P[FEAT];
    int g = blockIdx.x;
    int t = threadIdx.x;
    float c = fmaxf(cnt[g], 1.0f);
    P[t] = pooled[(size_t)g * FEAT + t] / c;
    __syncthreads();
    if (t < 8) {
        float acc = bfc[t];
        #pragma unroll
        for (int f = 0; f < FEAT; ++f) acc += P[f] * Wfc[f * 8 + t];
        out[(size_t)g * 8 + t] = 1.f / (1.f + expf(-acc));
    }
}

// ---------------------------------------------------------------------------

extern "C" void kernel_launch(void* const* d_in, const int* in_sizes, int n_in,
                              void* d_out, int out_size, void* d_ws, size_t ws_size,
                              hipStream_t stream) {
    const float* x    = (const float*)d_in[0];
    const int*   ei   = (const int*)d_in[1];
    const int*   batch= (const int*)d_in[2];
    const float* W0   = (const float*)d_in[3];
    const float* b0   = (const float*)d_in[4];
    const float* W1   = (const float*)d_in[5];
    const float* b1   = (const float*)d_in[6];
    const float* W2   = (const float*)d_in[7];
    const float* b2   = (const float*)d_in[8];
    const float* Wfc  = (const float*)d_in[9];
    const float* bfc  = (const float*)d_in[10];
    float* out = (float*)d_out;

    const int N = in_sizes[0] / FEAT;   // 100000
    const int E = in_sizes[1] / 2;      // 1250000
    const int G = out_size / 8;         // 512

    float* ws       = (float*)d_ws;
    float* bufA     = ws;
    float* bufB     = bufA + (size_t)N * FEAT;
    float* htmp     = bufB + (size_t)N * FEAT;
    float* dinv     = htmp + (size_t)N * FEAT;
    float* pooled   = dinv + N;
    float* cnt      = pooled + (size_t)G * FEAT;
    float* csr_coef = cnt + G;
    int*   deg_i    = (int*)(csr_coef + E);
    int*   off      = deg_i + N;
    int*   cursor   = off + (N + 1);
    int*   csr_src  = cursor + N;

    const int TB = 256;
    dim3 blk(TB);
    dim3 gN((N + TB - 1) / TB);
    dim3 gE((E + TB - 1) / TB);

    // --- CSR build (once per call) ---
    k_zero_int<<<gN, blk, 0, stream>>>(deg_i, N);
    k_hist<<<gE, blk, 0, stream>>>(ei, deg_i, E);
    k_dinv<<<gN, blk, 0, stream>>>(deg_i, dinv, N);
    k_scan<<<dim3(1), dim3(1024), 0, stream>>>(deg_i, off, cursor, N);
    k_scatter<<<gE, blk, 0, stream>>>(ei, dinv, cursor, csr_src, csr_coef, E);

    dim3 gAgg((N + 3) / 4);          // 4 waves (nodes) per 256-thr block
    dim3 gMM(2048);

    // --- layer 0: x -> bufA ---
    k_matmul_init<<<gMM, blk, 0, stream>>>(x, W0, b0, dinv, htmp, bufA, N);
    k_agg<<<gAgg, blk, 0, stream>>>(off, csr_src, csr_coef, htmp, bufA, N);

    // --- layer 1: bufA -> bufB ---
    k_matmul_init<<<gMM, blk, 0, stream>>>(bufA, W1, b1, dinv, htmp, bufB, N);
    k_agg<<<gAgg, blk, 0, stream>>>(off, csr_src, csr_coef, htmp, bufB, N);

    // --- layer 2: bufB -> bufA ---
    k_matmul_init<<<gMM, blk, 0, stream>>>(bufB, W2, b2, dinv, htmp, bufA, N);
    k_agg<<<gAgg, blk, 0, stream>>>(off, csr_src, csr_coef, htmp, bufA, N);

    // --- pooling + FC + sigmoid ---
    k_zero_f<<<dim3((G * (FEAT + 1) + TB - 1) / TB), blk, 0, stream>>>(pooled, G * (FEAT + 1));
    k_pool<<<dim3(((N + PCH - 1) / PCH + 3) / 4), blk, 0, stream>>>(bufA, batch, pooled, cnt, N);
    k_fc_sigmoid<<<dim3(G), dim3(FEAT), 0, stream>>>(pooled, cnt, Wfc, bfc, out, G);
}

// Round 3
// 483.328 us; speedup vs baseline: 2.5613x; 1.3507x over previous
//
#include <hip/hip_runtime.h>
#include <math.h>

// ---------------------------------------------------------------------------
// GCN: 3x GCNConv(64->64)+ReLU, mean pool (512 graphs), FC(64->8), sigmoid.
// N=100000, E=1250000. CSR-by-dst build (hierarchical scan) + gather agg.
// ---------------------------------------------------------------------------

#define FEAT 64
#define SCAN_BS 1024   // elements per scan block

// ---- degree / CSR build ----------------------------------------------------

__global__ void k_zero_int(int* __restrict__ p, int n) {
    int i = blockIdx.x * blockDim.x + threadIdx.x;
    if (i < n) p[i] = 0;
}

__global__ void k_hist(const int* __restrict__ ei, int* __restrict__ deg, int E) {
    int e = blockIdx.x * blockDim.x + threadIdx.x;
    if (e < E) atomicAdd(&deg[ei[E + e]], 1);  // dst = ei[1][e]
}

__global__ void k_dinv(const int* __restrict__ deg, float* __restrict__ dinv, int n) {
    int i = blockIdx.x * blockDim.x + threadIdx.x;
    if (i < n) dinv[i] = rsqrtf((float)deg[i] + 1.0f);  // +1 self-loop
}

// scan stage 1: per-block inclusive scan of 1024-chunk -> off (excl, local), bsum
__global__ void k_scan1(const int* __restrict__ deg, int* __restrict__ off,
                        int* __restrict__ bsum, int N) {
    __shared__ int sdata[SCAN_BS];
    int tid = threadIdx.x;
    int i = blockIdx.x * SCAN_BS + tid;
    int v = (i < N) ? deg[i] : 0;
    sdata[tid] = v;
    __syncthreads();
    for (int d = 1; d < SCAN_BS; d <<= 1) {
        int t = (tid >= d) ? sdata[tid - d] : 0;
        __syncthreads();
        sdata[tid] += t;
        __syncthreads();
    }
    if (i < N) off[i] = sdata[tid] - v;            // block-local exclusive
    if (tid == SCAN_BS - 1) bsum[blockIdx.x] = sdata[tid];
}

// scan stage 2: single block scans the block sums (nb <= 1024), writes off[N]
__global__ void k_scan2(int* __restrict__ bsum, int* __restrict__ offN, int nb) {
    __shared__ int sdata[SCAN_BS];
    int tid = threadIdx.x;
    int v = (tid < nb) ? bsum[tid] : 0;
    sdata[tid] = v;
    __syncthreads();
    for (int d = 1; d < SCAN_BS; d <<= 1) {
        int t = (tid >= d) ? sdata[tid - d] : 0;
        __syncthreads();
        sdata[tid] += t;
        __syncthreads();
    }
    if (tid < nb) bsum[tid] = sdata[tid] - v;      // exclusive base per block
    if (tid == nb - 1) *offN = sdata[tid];         // total = E
}

// scan stage 3: add block base, fill cursor
__global__ void k_scan3(int* __restrict__ off, int* __restrict__ cursor,
                        const int* __restrict__ bsum, int N) {
    int i = blockIdx.x * blockDim.x + threadIdx.x;
    if (i < N) {
        int o = off[i] + bsum[i >> 10];
        off[i] = o;
        cursor[i] = o;
    }
}

__global__ void k_scatter(const int* __restrict__ ei, const float* __restrict__ dinv,
                          int* __restrict__ cursor, int* __restrict__ csr_src,
                          float* __restrict__ csr_coef, int E) {
    int e = blockIdx.x * blockDim.x + threadIdx.x;
    if (e < E) {
        int s = ei[e];
        int d = ei[E + e];
        int pos = atomicAdd(&cursor[d], 1);
        csr_src[pos] = s;
        csr_coef[pos] = dinv[s] * dinv[d];
    }
}

// ---- dense parts -----------------------------------------------------------

// h = X @ W ; out_init = h * dinv^2 + b   (self-loop term + bias pre-filled)
__global__ void k_matmul_init(const float* __restrict__ X, const float* __restrict__ W,
                              const float* __restrict__ b, const float* __restrict__ dinv,
                              float* __restrict__ h, float* __restrict__ out, int n) {
    __shared__ float Ws[FEAT][FEAT];
    __shared__ float Xs[4][FEAT];
    int f = threadIdx.x & 63;
    int r = threadIdx.x >> 6;  // 0..3
    for (int i = threadIdx.x; i < FEAT * FEAT; i += 256) Ws[i >> 6][i & 63] = W[i];
    float bf = b[f];
    int ntiles = (n + 3) >> 2;
    for (int tile = blockIdx.x; tile < ntiles; tile += gridDim.x) {
        int row = (tile << 2) + r;
        __syncthreads();
        if (row < n) Xs[r][f] = X[(size_t)row * FEAT + f];
        __syncthreads();
        if (row < n) {
            float acc = 0.f;
            #pragma unroll
            for (int k = 0; k < FEAT; ++k) acc += Xs[r][k] * Ws[k][f];
            float dv = dinv[row];
            size_t o = (size_t)row * FEAT + f;
            h[o] = acc;
            out[o] = acc * dv * dv + bf;
        }
    }
}

// out[dst] = relu(out[dst] + sum_j h[src_j]*coef_j)  -- 1 wave per dst node
__global__ void k_agg(const int* __restrict__ off, const int* __restrict__ csr_src,
                      const float* __restrict__ csr_coef, const float* __restrict__ h,
                      float* __restrict__ out, int N) {
    int node = blockIdx.x * (blockDim.x >> 6) + (threadIdx.x >> 6);
    int f = threadIdx.x & 63;
    if (node >= N) return;
    int j = off[node], e1 = off[node + 1];
    float acc = 0.f;
    for (; j + 4 <= e1; j += 4) {
        int s0 = csr_src[j], s1 = csr_src[j + 1], s2 = csr_src[j + 2], s3 = csr_src[j + 3];
        float c0 = csr_coef[j], c1 = csr_coef[j + 1], c2 = csr_coef[j + 2], c3 = csr_coef[j + 3];
        acc += h[(size_t)s0 * FEAT + f] * c0;
        acc += h[(size_t)s1 * FEAT + f] * c1;
        acc += h[(size_t)s2 * FEAT + f] * c2;
        acc += h[(size_t)s3 * FEAT + f] * c3;
    }
    for (; j < e1; ++j) acc += h[(size_t)csr_src[j] * FEAT + f] * csr_coef[j];
    size_t o = (size_t)node * FEAT + f;
    out[o] = fmaxf(out[o] + acc, 0.f);
}

// ---- pooling + FC ----------------------------------------------------------

__global__ void k_zero_f(float* __restrict__ p, int n) {
    int i = blockIdx.x * blockDim.x + threadIdx.x;
    if (i < n) p[i] = 0.f;
}

// batch is sorted: chunked per-wave reduction, flush on graph-id change
#define PCH 64
__global__ void k_pool(const float* __restrict__ h, const int* __restrict__ batch,
                       float* __restrict__ pooled, float* __restrict__ cnt, int N) {
    int wave = blockIdx.x * (blockDim.x >> 6) + (threadIdx.x >> 6);
    int f = threadIdx.x & 63;
    int start = wave * PCH;
    if (start >= N) return;
    int end = start + PCH; if (end > N) end = N;
    int cur = batch[start];
    float acc = 0.f;
    int nl = 0;
    for (int i = start; i < end; ++i) {
        int g = batch[i];
        if (g != cur) {
            atomicAdd(&pooled[(size_t)cur * FEAT + f], acc);
            if (f == 0) atomicAdd(&cnt[cur], (float)nl);
            cur = g; acc = 0.f; nl = 0;
        }
        acc += h[(size_t)i * FEAT + f];
        nl++;
    }
    atomicAdd(&pooled[(size_t)cur * FEAT + f], acc);
    if (f == 0) atomicAdd(&cnt[cur], (float)nl);
}

__global__ void k_fc_sigmoid(const float* __restrict__ pooled, const float* __restrict__ cnt,
                             const float* __restrict__ Wfc, const float* __restrict__ bfc,
                             float* __restrict__ out, int G) {
    __shared__ float P[FEAT];
    int g = blockIdx.x;
    int t = threadIdx.x;
    float c = fmaxf(cnt[g], 1.0f);
    P[t] = pooled[(size_t)g * FEAT + t] / c;
    __syncthreads();
    if (t < 8) {
        float acc = bfc[t];
        #pragma unroll
        for (int f = 0; f < FEAT; ++f) acc += P[f] * Wfc[f * 8 + t];
        out[(size_t)g * 8 + t] = 1.f / (1.f + expf(-acc));
    }
}

// ---------------------------------------------------------------------------

extern "C" void kernel_launch(void* const* d_in, const int* in_sizes, int n_in,
                              void* d_out, int out_size, void* d_ws, size_t ws_size,
                              hipStream_t stream) {
    const float* x    = (const float*)d_in[0];
    const int*   ei   = (const int*)d_in[1];
    const int*   batch= (const int*)d_in[2];
    const float* W0   = (const float*)d_in[3];
    const float* b0   = (const float*)d_in[4];
    const float* W1   = (const float*)d_in[5];
    const float* b1   = (const float*)d_in[6];
    const float* W2   = (const float*)d_in[7];
    const float* b2   = (const float*)d_in[8];
    const float* Wfc  = (const float*)d_in[9];
    const float* bfc  = (const float*)d_in[10];
    float* out = (float*)d_out;

    const int N = in_sizes[0] / FEAT;   // 100000
    const int E = in_sizes[1] / 2;      // 1250000
    const int G = out_size / 8;         // 512
    const int NB = (N + SCAN_BS - 1) / SCAN_BS;   // 98 scan blocks

    float* ws       = (float*)d_ws;
    float* bufA     = ws;
    float* bufB     = bufA + (size_t)N * FEAT;
    float* htmp     = bufB + (size_t)N * FEAT;
    float* dinv     = htmp + (size_t)N * FEAT;
    float* pooled   = dinv + N;
    float* cnt      = pooled + (size_t)G * FEAT;
    float* csr_coef = cnt + G;
    int*   deg_i    = (int*)(csr_coef + E);
    int*   off      = deg_i + N;
    int*   cursor   = off + (N + 1);
    int*   csr_src  = cursor + N;
    int*   bsum     = csr_src + E;

    const int TB = 256;
    dim3 blk(TB);
    dim3 gN((N + TB - 1) / TB);
    dim3 gE((E + TB - 1) / TB);

    // --- CSR build (once per call) ---
    k_zero_int<<<gN, blk, 0, stream>>>(deg_i, N);
    k_hist<<<gE, blk, 0, stream>>>(ei, deg_i, E);
    k_dinv<<<gN, blk, 0, stream>>>(deg_i, dinv, N);
    k_scan1<<<dim3(NB), dim3(SCAN_BS), 0, stream>>>(deg_i, off, bsum, N);
    k_scan2<<<dim3(1), dim3(SCAN_BS), 0, stream>>>(bsum, off + N, NB);
    k_scan3<<<gN, blk, 0, stream>>>(off, cursor, bsum, N);
    k_scatter<<<gE, blk, 0, stream>>>(ei, dinv, cursor, csr_src, csr_coef, E);

    dim3 gAgg((N + 3) / 4);          // 4 waves (nodes) per 256-thr block
    dim3 gMM(2048);

    // --- layer 0: x -> bufA ---
    k_matmul_init<<<gMM, blk, 0, stream>>>(x, W0, b0, dinv, htmp, bufA, N);
    k_agg<<<gAgg, blk, 0, stream>>>(off, csr_src, csr_coef, htmp, bufA, N);

    // --- layer 1: bufA -> bufB ---
    k_matmul_init<<<gMM, blk, 0, stream>>>(bufA, W1, b1, dinv, htmp, bufB, N);
    k_agg<<<gAgg, blk, 0, stream>>>(off, csr_src, csr_coef, htmp, bufB, N);

    // --- layer 2: bufB -> bufA ---
    k_matmul_init<<<gMM, blk, 0, stream>>>(bufB, W2, b2, dinv, htmp, bufA, N);
    k_agg<<<gAgg, blk, 0, stream>>>(off, csr_src, csr_coef, htmp, bufA, N);

    // --- pooling + FC + sigmoid ---
    k_zero_f<<<dim3((G * (FEAT + 1) + TB - 1) / TB), blk, 0, stream>>>(pooled, G * (FEAT + 1));
    k_pool<<<dim3(((N + PCH - 1) / PCH + 3) / 4), blk, 0, stream>>>(bufA, batch, pooled, cnt, N);
    k_fc_sigmoid<<<dim3(G), dim3(FEAT), 0, stream>>>(pooled, cnt, Wfc, bfc, out, G);
}